// Round 1
// baseline (685.997 us; speedup 1.0000x reference)
//
#include <hip/hip_runtime.h>
#include <hip/hip_bf16.h>

#define HW 4096
#define CIN 192
#define CMID 96

typedef __attribute__((ext_vector_type(8))) short bf16x8;
typedef __attribute__((ext_vector_type(4))) float f32x4;

static __device__ __forceinline__ unsigned short f2bf(float f) {
    union { float f; unsigned int u; } v;
    v.f = f;
    unsigned int r = v.u + 0x7fffu + ((v.u >> 16) & 1u);
    return (unsigned short)(r >> 16);
}

// ---------------------------------------------------------------------------
// Kernel 1: xpe = x + pe;  q/k/v = W * xpe + b  (per 64-pixel tile, fp32)
// Q,K stored [n][i][96] bf16 (channel-contiguous), V stored [n][96][i] bf16.
// ---------------------------------------------------------------------------
__global__ __launch_bounds__(256) void qkv_kernel(
    const float* __restrict__ x, const float* __restrict__ pe,
    const float* __restrict__ wq, const float* __restrict__ bq,
    const float* __restrict__ wk, const float* __restrict__ bk,
    const float* __restrict__ wv, const float* __restrict__ bv,
    float* __restrict__ xpe,
    unsigned short* __restrict__ Q, unsigned short* __restrict__ K,
    unsigned short* __restrict__ V)
{
    const int n  = blockIdx.y;
    const int i0 = blockIdx.x * 64;
    const int tid = threadIdx.x;

    __shared__ float xs[CIN][64];          // staged xpe tile
    __shared__ unsigned short outs[64 * 97]; // padded transpose buffer

    // stage x + pe (coalesced), also write xpe for the final residual
    for (int idx = tid; idx < CIN * 64; idx += 256) {
        int c = idx >> 6, il = idx & 63;
        int i = i0 + il;
        float v = x[((size_t)n * CIN + c) * HW + i]
                + pe[c * 14400 + (i >> 6) * 120 + (i & 63)];
        xs[c][il] = v;
        xpe[((size_t)n * CIN + c) * HW + i] = v;
    }
    __syncthreads();

    const int il = tid & 63;      // pixel within tile
    const int cg = tid >> 6;      // 4 groups of 24 output channels

    for (int m = 0; m < 3; ++m) {
        const float* W = (m == 0) ? wq : ((m == 1) ? wk : wv);
        const float* B = (m == 0) ? bq : ((m == 1) ? bk : bv);

        float acc[24];
        #pragma unroll
        for (int j = 0; j < 24; ++j) acc[j] = B[cg * 24 + j];

        for (int cb = 0; cb < 12; ++cb) {
            float xr[16];
            #pragma unroll
            for (int j = 0; j < 16; ++j) xr[j] = xs[cb * 16 + j][il];
            #pragma unroll
            for (int co8 = 0; co8 < 24; ++co8) {
                const float* wr = W + (cg * 24 + co8) * CIN + cb * 16;
                #pragma unroll
                for (int j = 0; j < 16; ++j)
                    acc[co8] = fmaf(wr[j], xr[j], acc[co8]);
            }
        }

        if (m < 2) {
            // transpose through LDS so global stores are coalesced
            __syncthreads();   // prior copy-out done (no-op on first pass)
            #pragma unroll
            for (int j = 0; j < 24; ++j)
                outs[il * 97 + cg * 24 + j] = f2bf(acc[j]);
            __syncthreads();
            unsigned short* dst = ((m == 0) ? Q : K) + ((size_t)n * HW + i0) * CMID;
            for (int idx = tid; idx < 64 * CMID; idx += 256) {
                int i = idx / CMID, c = idx - i * CMID;
                dst[idx] = outs[i * 97 + c];
            }
        } else {
            // V goes out transposed [c][i]: lanes (=il) are already coalesced
            #pragma unroll
            for (int j = 0; j < 24; ++j) {
                int co = cg * 24 + j;
                V[((size_t)n * CMID + co) * HW + i0 + il] = f2bf(acc[j]);
            }
        }
    }
}

// ---------------------------------------------------------------------------
// Kernel 2: flash attention.  4 independent waves/block, 16 q-rows each.
// S = Q K^T * (1/64), online softmax (base-2 domain), O += P V.
// ---------------------------------------------------------------------------
__global__ __launch_bounds__(256) void attn_kernel(
    const unsigned short* __restrict__ Q, const unsigned short* __restrict__ K,
    const unsigned short* __restrict__ V, float* __restrict__ z)
{
    const int n    = blockIdx.y;
    const int wave = threadIdx.x >> 6;
    const int lane = threadIdx.x & 63;
    const int ib   = blockIdx.x * 64 + wave * 16;   // first q-row of this wave
    const int l15  = lane & 15;
    const int lg   = lane >> 4;

    __shared__ unsigned short plds_all[4][16 * 72];  // per-wave P tile, padded
    unsigned short* plds = plds_all[wave];

    const unsigned short* Qb = Q + (size_t)n * HW * CMID;
    const unsigned short* Kb = K + (size_t)n * HW * CMID;
    const unsigned short* Vb = V + (size_t)n * CMID * HW;

    // Q fragments, hoisted (A-frag: row = l&15, k = (l>>4)*8 + e)
    bf16x8 qf[3];
    #pragma unroll
    for (int f = 0; f < 3; ++f)
        qf[f] = *(const bf16x8*)(Qb + ((size_t)(ib + l15)) * CMID + f * 32 + lg * 8);

    f32x4 O[6];
    #pragma unroll
    for (int ct = 0; ct < 6; ++ct) O[ct] = (f32x4){0.f, 0.f, 0.f, 0.f};
    float mrow[4], lrow[4];
    #pragma unroll
    for (int r = 0; r < 4; ++r) { mrow[r] = -1e30f; lrow[r] = 0.f; }

    const float sc = 0.015625f * 1.44269504089f;  // (1/64) * log2(e)

    for (int j0 = 0; j0 < HW; j0 += 64) {
        // ---- S tiles: 4 subtiles of 16 j, K over 96 channels (3 mfma each)
        f32x4 st[4];
        #pragma unroll
        for (int jt = 0; jt < 4; ++jt) {
            f32x4 s = (f32x4){0.f, 0.f, 0.f, 0.f};
            #pragma unroll
            for (int f = 0; f < 3; ++f) {
                bf16x8 kf = *(const bf16x8*)(Kb + ((size_t)(j0 + jt * 16 + l15)) * CMID
                                              + f * 32 + lg * 8);
                s = __builtin_amdgcn_mfma_f32_16x16x32_bf16(qf[f], kf, s, 0, 0, 0);
            }
            st[jt] = s;
        }

        // ---- online softmax (rows = lg*4 + r, cols spread over 16 lanes)
        float mnew[4], alpha[4], p[4][4], rs[4];
        #pragma unroll
        for (int r = 0; r < 4; ++r) {
            float t = fmaxf(fmaxf(st[0][r], st[1][r]), fmaxf(st[2][r], st[3][r])) * sc;
            t = fmaxf(t, __shfl_xor(t, 1));
            t = fmaxf(t, __shfl_xor(t, 2));
            t = fmaxf(t, __shfl_xor(t, 4));
            t = fmaxf(t, __shfl_xor(t, 8));
            mnew[r] = fmaxf(mrow[r], t);
            alpha[r] = exp2f(mrow[r] - mnew[r]);
            mrow[r] = mnew[r];
        }
        #pragma unroll
        for (int r = 0; r < 4; ++r) {
            float s0 = exp2f(st[0][r] * sc - mnew[r]);
            float s1 = exp2f(st[1][r] * sc - mnew[r]);
            float s2 = exp2f(st[2][r] * sc - mnew[r]);
            float s3 = exp2f(st[3][r] * sc - mnew[r]);
            p[0][r] = s0; p[1][r] = s1; p[2][r] = s2; p[3][r] = s3;
            float sum = (s0 + s1) + (s2 + s3);
            sum += __shfl_xor(sum, 1);
            sum += __shfl_xor(sum, 2);
            sum += __shfl_xor(sum, 4);
            sum += __shfl_xor(sum, 8);
            rs[r] = sum;
            lrow[r] = lrow[r] * alpha[r] + rs[r];
        }
        #pragma unroll
        for (int ct = 0; ct < 6; ++ct) {
            #pragma unroll
            for (int r = 0; r < 4; ++r) O[ct][r] *= alpha[r];
        }

        // ---- P -> LDS (bf16), re-read as A-fragments
        #pragma unroll
        for (int jt = 0; jt < 4; ++jt) {
            #pragma unroll
            for (int r = 0; r < 4; ++r)
                plds[(lg * 4 + r) * 72 + jt * 16 + l15] = f2bf(p[jt][r]);
        }
        bf16x8 pf0 = *(const bf16x8*)(plds + l15 * 72 + lg * 8);
        bf16x8 pf1 = *(const bf16x8*)(plds + l15 * 72 + lg * 8 + 32);

        // ---- O += P V  (B-frag from V^T: col = l&15 (channel), k = j contiguous)
        #pragma unroll
        for (int ct = 0; ct < 6; ++ct) {
            bf16x8 vf0 = *(const bf16x8*)(Vb + ((size_t)(ct * 16 + l15)) * HW + j0 + lg * 8);
            O[ct] = __builtin_amdgcn_mfma_f32_16x16x32_bf16(pf0, vf0, O[ct], 0, 0, 0);
            bf16x8 vf1 = *(const bf16x8*)(Vb + ((size_t)(ct * 16 + l15)) * HW + j0 + 32 + lg * 8);
            O[ct] = __builtin_amdgcn_mfma_f32_16x16x32_bf16(pf1, vf1, O[ct], 0, 0, 0);
        }
    }

    // ---- epilogue: divide by l, write z[n][i][c] (f32)
    float linv[4];
    #pragma unroll
    for (int r = 0; r < 4; ++r) linv[r] = 1.f / lrow[r];
    #pragma unroll
    for (int ct = 0; ct < 6; ++ct) {
        #pragma unroll
        for (int r = 0; r < 4; ++r) {
            int i = ib + lg * 4 + r;
            z[((size_t)n * HW + i) * CMID + ct * 16 + l15] = O[ct][r] * linv[r];
        }
    }
}

// ---------------------------------------------------------------------------
// Kernel 3: out = xpe + Wz * z + bz   (fp32, LDS-staged z tile)
// ---------------------------------------------------------------------------
__global__ __launch_bounds__(256) void zproj_kernel(
    const float* __restrict__ z, const float* __restrict__ wz,
    const float* __restrict__ bz, const float* __restrict__ xpe,
    float* __restrict__ out)
{
    const int n  = blockIdx.y;
    const int i0 = blockIdx.x * 64;
    const int tid = threadIdx.x;

    __shared__ float zs[64 * 97];
    for (int idx = tid; idx < 64 * CMID; idx += 256) {
        int i = idx / CMID, c = idx - i * CMID;
        zs[i * 97 + c] = z[((size_t)n * HW + i0 + i) * CMID + c];
    }
    __syncthreads();

    const int il = tid & 63;
    const int cg = tid >> 6;   // 4 groups of 48 output channels

    float acc[48];
    #pragma unroll
    for (int j = 0; j < 48; ++j) acc[j] = bz[cg * 48 + j];

    for (int cb = 0; cb < 6; ++cb) {
        float zr[16];
        #pragma unroll
        for (int j = 0; j < 16; ++j) zr[j] = zs[il * 97 + cb * 16 + j];
        #pragma unroll
        for (int co8 = 0; co8 < 48; ++co8) {
            const float* wr = wz + (cg * 48 + co8) * CMID + cb * 16;
            #pragma unroll
            for (int j = 0; j < 16; ++j)
                acc[co8] = fmaf(wr[j], zr[j], acc[co8]);
        }
    }

    #pragma unroll
    for (int j = 0; j < 48; ++j) {
        int co = cg * 48 + j;
        size_t a = ((size_t)n * CIN + co) * HW + i0 + il;
        out[a] = xpe[a] + acc[j];
    }
}

// ---------------------------------------------------------------------------
extern "C" void kernel_launch(void* const* d_in, const int* in_sizes, int n_in,
                              void* d_out, int out_size, void* d_ws, size_t ws_size,
                              hipStream_t stream) {
    const float* x  = (const float*)d_in[0];
    const float* pe = (const float*)d_in[1];
    const float* wq = (const float*)d_in[2];
    const float* bq = (const float*)d_in[3];
    const float* wk = (const float*)d_in[4];
    const float* bk = (const float*)d_in[5];
    const float* wv = (const float*)d_in[6];
    const float* bv = (const float*)d_in[7];
    const float* wz = (const float*)d_in[8];
    const float* bz = (const float*)d_in[9];
    float* out = (float*)d_out;

    char* ws = (char*)d_ws;
    // workspace layout (bytes):
    //   xpe f32 : 8*192*4096*4 = 25,165,824
    //   Q   bf16: 8*4096*96*2  =  6,291,456
    //   K   bf16:                 6,291,456
    //   V^T bf16:                 6,291,456
    //   z   f32 : 8*4096*96*4  = 12,582,912   (total 56,623,104)
    float*          xpe = (float*)ws;
    unsigned short* Qb  = (unsigned short*)(ws + 25165824);
    unsigned short* Kb  = (unsigned short*)(ws + 31457280);
    unsigned short* Vb  = (unsigned short*)(ws + 37748736);
    float*          zb  = (float*)(ws + 44040192);

    dim3 grid(64, 8);
    qkv_kernel<<<grid, 256, 0, stream>>>(x, pe, wq, bq, wk, bk, wv, bv,
                                         xpe, Qb, Kb, Vb);
    attn_kernel<<<grid, 256, 0, stream>>>(Qb, Kb, Vb, zb);
    zproj_kernel<<<grid, 256, 0, stream>>>(zb, wz, bz, xpe, out);
}

// Round 2
// 160.490 us; speedup vs baseline: 4.2744x; 4.2744x over previous
//
#include <hip/hip_runtime.h>
#include <hip/hip_bf16.h>

#define HW 4096
#define CIN 192
#define CMID 96

typedef __attribute__((ext_vector_type(8))) short bf16x8;
typedef __attribute__((ext_vector_type(4))) float f32x4;

static __device__ __forceinline__ unsigned short f2bf(float f) {
    union { float f; unsigned int u; } v;
    v.f = f;
    unsigned int r = v.u + 0x7fffu + ((v.u >> 16) & 1u);
    return (unsigned short)(r >> 16);
}

static __device__ __forceinline__ void gload16(const void* g, void* l) {
    __builtin_amdgcn_global_load_lds(
        (const __attribute__((address_space(1))) unsigned int*)g,
        (__attribute__((address_space(3))) unsigned int*)l, 16, 0, 0);
}

// ---------------------------------------------------------------------------
// Kernel 0: convert weights to bf16.  wqkvb: [3*96][192], wzb: [192][96]
// ---------------------------------------------------------------------------
__global__ __launch_bounds__(256) void convw_kernel(
    const float* __restrict__ wq, const float* __restrict__ wk,
    const float* __restrict__ wv, const float* __restrict__ wz,
    unsigned short* __restrict__ wqkvb, unsigned short* __restrict__ wzb)
{
    int idx = blockIdx.x * 256 + threadIdx.x;
    if (idx < 3 * CMID * CIN) {
        int m = idx / (CMID * CIN), r = idx % (CMID * CIN);
        const float* w = (m == 0) ? wq : ((m == 1) ? wk : wv);
        wqkvb[idx] = f2bf(w[r]);
    } else if (idx < 3 * CMID * CIN + CIN * CMID) {
        int r = idx - 3 * CMID * CIN;
        wzb[r] = f2bf(wz[r]);
    }
}

// ---------------------------------------------------------------------------
// Kernel 1: Q/K/V projections as bf16 MFMA GEMM.
// ---------------------------------------------------------------------------
__global__ __launch_bounds__(256) void qkv_kernel(
    const float* __restrict__ x, const float* __restrict__ pe,
    const unsigned short* __restrict__ wqkvb,
    const float* __restrict__ bq, const float* __restrict__ bk,
    const float* __restrict__ bv,
    unsigned short* __restrict__ Q, unsigned short* __restrict__ K,
    unsigned short* __restrict__ V)
{
    const int n = blockIdx.y, i0 = blockIdx.x * 64, t = threadIdx.x;
    __shared__ unsigned short xt[64 * 200];

    for (int idx = t; idx < CIN * 64; idx += 256) {
        int c = idx >> 6, il = idx & 63;
        float v = x[((size_t)n * CIN + c) * HW + i0 + il]
                + pe[c * 14400 + blockIdx.x * 120 + il];
        xt[il * 200 + c] = f2bf(v);
    }
    __syncthreads();

    const int w = t >> 6, lane = t & 63, l15 = lane & 15, lg = lane >> 4;
    const int p0 = w * 16;

    bf16x8 af[6];
    #pragma unroll
    for (int f = 0; f < 6; ++f)
        af[f] = *(const bf16x8*)(xt + (p0 + l15) * 200 + f * 32 + lg * 8);

    #pragma unroll
    for (int ct = 0; ct < 18; ++ct) {
        f32x4 acc = (f32x4){0.f, 0.f, 0.f, 0.f};
        const unsigned short* wrow = wqkvb + (ct * 16 + l15) * CIN + lg * 8;
        #pragma unroll
        for (int f = 0; f < 6; ++f) {
            bf16x8 wf = *(const bf16x8*)(wrow + f * 32);
            acc = __builtin_amdgcn_mfma_f32_16x16x32_bf16(af[f], wf, acc, 0, 0, 0);
        }
        const int m = ct / 6, c6 = ct % 6, co = c6 * 16 + l15;
        const float bias = ((m == 0) ? bq : (m == 1) ? bk : bv)[co];
        if (m < 2) {
            unsigned short* dst = ((m == 0) ? Q : K) + (size_t)n * HW * CMID;
            #pragma unroll
            for (int r = 0; r < 4; ++r) {
                int i = i0 + p0 + lg * 4 + r;
                dst[(size_t)i * CMID + co] = f2bf(acc[r] + bias);
            }
        } else {
            ushort4 pk;
            pk.x = f2bf(acc[0] + bias); pk.y = f2bf(acc[1] + bias);
            pk.z = f2bf(acc[2] + bias); pk.w = f2bf(acc[3] + bias);
            int ibase = i0 + p0 + lg * 4;
            *(ushort4*)(V + (size_t)n * CMID * HW + (size_t)co * HW + ibase) = pk;
        }
    }
}

// ---------------------------------------------------------------------------
// Kernel 2: attention core (no-max softmax, j-split over 2 block sets).
// ---------------------------------------------------------------------------
__global__ __launch_bounds__(256, 2) void attn_kernel(
    const unsigned short* __restrict__ Q, const unsigned short* __restrict__ K,
    const unsigned short* __restrict__ V,
    float* __restrict__ zp, float* __restrict__ lp)
{
    const int bid = blockIdx.x;
    const int xcd = bid & 7, kk_ = bid >> 3;
    const int g = xcd + 8 * (kk_ >> 5);
    const int bx = kk_ & 31;
    const int n = g >> 1, jh = g & 1;

    const int t = threadIdx.x, w = t >> 6, lane = t & 63;
    const int l15 = lane & 15, lg = lane >> 4;
    const int ib = bx * 128 + w * 32;

    __shared__ unsigned short Ks[2][64 * 128];
    __shared__ unsigned short Vs[2][96 * 64];
    __shared__ unsigned short Ps[4][32 * 72];

    const unsigned short* Qb = Q + (size_t)n * HW * CMID;
    const unsigned short* Kb = K + (size_t)n * HW * CMID;
    const unsigned short* Vb = V + (size_t)n * CMID * HW;

    bf16x8 qf[2][3];
    #pragma unroll
    for (int rg = 0; rg < 2; ++rg)
        #pragma unroll
        for (int f = 0; f < 3; ++f)
            qf[rg][f] = *(const bf16x8*)(Qb + (size_t)(ib + rg * 16 + l15) * CMID
                                          + f * 32 + lg * 8);

    int ksoff[4], vsoff[3];
    #pragma unroll
    for (int s = 0; s < 4; ++s) {
        int row = 4 * (w * 4 + s) + (lane >> 4);
        ksoff[s] = row * CMID + (((lane & 15) ^ (row & 7)) * 8);
    }
    #pragma unroll
    for (int s = 0; s < 3; ++s) {
        int c = 8 * (w * 3 + s) + (lane >> 3);
        vsoff[s] = c * HW + (((lane & 7) ^ (c & 7)) * 8);
    }

#define STAGE(J0, BUF) do {                                                        \
    _Pragma("unroll") for (int s = 0; s < 4; ++s)                                  \
        gload16(Kb + (size_t)(J0) * CMID + ksoff[s], &Ks[BUF][(w * 4 + s) * 512]); \
    _Pragma("unroll") for (int s = 0; s < 3; ++s)                                  \
        gload16(Vb + (size_t)(J0) + vsoff[s], &Vs[BUF][(w * 3 + s) * 512]);        \
} while (0)

    const int j00 = jh * 2048;
    STAGE(j00, 0);

    f32x4 O[2][6];
    #pragma unroll
    for (int rg = 0; rg < 2; ++rg)
        #pragma unroll
        for (int ct = 0; ct < 6; ++ct) O[rg][ct] = (f32x4){0.f, 0.f, 0.f, 0.f};
    float lsum[2][4] = {{0.f,0.f,0.f,0.f},{0.f,0.f,0.f,0.f}};

    const float SC = 0.015625f * 1.44269504089f;
    const int swz = (l15 & 7) << 3;

    __syncthreads();

    for (int tt = 0; tt < 32; ++tt) {
        if (tt < 31) STAGE(j00 + (tt + 1) * 64, (tt + 1) & 1);

        const unsigned short* Kc = Ks[tt & 1];
        const unsigned short* Vc = Vs[tt & 1];

        #pragma unroll
        for (int jt = 0; jt < 4; ++jt) {
            const int rb = (jt * 16 + l15) * 128;
            bf16x8 kf0 = *(const bf16x8*)(Kc + ((rb + 0 * 32 + lg * 8) ^ swz));
            bf16x8 kf1 = *(const bf16x8*)(Kc + ((rb + 1 * 32 + lg * 8) ^ swz));
            bf16x8 kf2 = *(const bf16x8*)(Kc + ((rb + 2 * 32 + lg * 8) ^ swz));
            f32x4 s0 = (f32x4){0.f,0.f,0.f,0.f}, s1 = (f32x4){0.f,0.f,0.f,0.f};
            s0 = __builtin_amdgcn_mfma_f32_16x16x32_bf16(qf[0][0], kf0, s0, 0,0,0);
            s1 = __builtin_amdgcn_mfma_f32_16x16x32_bf16(qf[1][0], kf0, s1, 0,0,0);
            s0 = __builtin_amdgcn_mfma_f32_16x16x32_bf16(qf[0][1], kf1, s0, 0,0,0);
            s1 = __builtin_amdgcn_mfma_f32_16x16x32_bf16(qf[1][1], kf1, s1, 0,0,0);
            s0 = __builtin_amdgcn_mfma_f32_16x16x32_bf16(qf[0][2], kf2, s0, 0,0,0);
            s1 = __builtin_amdgcn_mfma_f32_16x16x32_bf16(qf[1][2], kf2, s1, 0,0,0);
            #pragma unroll
            for (int r = 0; r < 4; ++r) {
                float p0 = exp2f(s0[r] * SC);
                float p1 = exp2f(s1[r] * SC);
                lsum[0][r] += p0;
                lsum[1][r] += p1;
                Ps[w][(lg * 4 + r) * 72 + jt * 16 + l15] = f2bf(p0);
                Ps[w][(16 + lg * 4 + r) * 72 + jt * 16 + l15] = f2bf(p1);
            }
        }

        bf16x8 pf[2][2];
        #pragma unroll
        for (int rg = 0; rg < 2; ++rg)
            #pragma unroll
            for (int kk = 0; kk < 2; ++kk)
                pf[rg][kk] = *(const bf16x8*)(Ps[w] + (rg * 16 + l15) * 72
                                               + kk * 32 + lg * 8);
        #pragma unroll
        for (int ct = 0; ct < 6; ++ct) {
            const int vb = (ct * 16 + l15) * 64;
            bf16x8 vf0 = *(const bf16x8*)(Vc + ((vb + 0 * 32 + lg * 8) ^ swz));
            bf16x8 vf1 = *(const bf16x8*)(Vc + ((vb + 1 * 32 + lg * 8) ^ swz));
            O[0][ct] = __builtin_amdgcn_mfma_f32_16x16x32_bf16(pf[0][0], vf0, O[0][ct], 0,0,0);
            O[1][ct] = __builtin_amdgcn_mfma_f32_16x16x32_bf16(pf[1][0], vf0, O[1][ct], 0,0,0);
            O[0][ct] = __builtin_amdgcn_mfma_f32_16x16x32_bf16(pf[0][1], vf1, O[0][ct], 0,0,0);
            O[1][ct] = __builtin_amdgcn_mfma_f32_16x16x32_bf16(pf[1][1], vf1, O[1][ct], 0,0,0);
        }
        __syncthreads();
    }
#undef STAGE

    float* zb = zp + ((size_t)jh * 8 + n) * HW * CMID;
    #pragma unroll
    for (int rg = 0; rg < 2; ++rg)
        #pragma unroll
        for (int ct = 0; ct < 6; ++ct)
            #pragma unroll
            for (int r = 0; r < 4; ++r)
                zb[(size_t)(ib + rg * 16 + lg * 4 + r) * CMID + ct * 16 + l15]
                    = O[rg][ct][r];

    float red[2][4];
    #pragma unroll
    for (int rg = 0; rg < 2; ++rg)
        #pragma unroll
        for (int r = 0; r < 4; ++r) {
            float s = lsum[rg][r];
            s += __shfl_xor(s, 1);
            s += __shfl_xor(s, 2);
            s += __shfl_xor(s, 4);
            s += __shfl_xor(s, 8);
            red[rg][r] = s;
        }
    if (l15 == 0) {
        float* lb = lp + ((size_t)jh * 8 + n) * HW;
        #pragma unroll
        for (int rg = 0; rg < 2; ++rg)
            #pragma unroll
            for (int r = 0; r < 4; ++r)
                lb[ib + rg * 16 + lg * 4 + r] = red[rg][r];
    }
}

// ---------------------------------------------------------------------------
// Kernel 3: combine halves, normalize, project back (MFMA), add residual.
// ---------------------------------------------------------------------------
__global__ __launch_bounds__(256) void zproj_kernel(
    const float* __restrict__ zp, const float* __restrict__ lp,
    const unsigned short* __restrict__ wzb, const float* __restrict__ bz,
    const float* __restrict__ x, const float* __restrict__ pe,
    float* __restrict__ out)
{
    const int n = blockIdx.y, i0 = blockIdx.x * 64, t = threadIdx.x;
    __shared__ unsigned short zt[64 * 104];
    __shared__ float ll[64];

    const float* zp0 = zp;
    const float* zp1 = zp + (size_t)8 * HW * CMID;
    const float* lp0 = lp;
    const float* lp1 = lp + (size_t)8 * HW;

    if (t < 64)
        ll[t] = 1.f / (lp0[(size_t)n * HW + i0 + t] + lp1[(size_t)n * HW + i0 + t]);
    __syncthreads();

    for (int idx = t; idx < 64 * CMID; idx += 256) {
        int i = idx / CMID, c = idx - i * CMID;
        size_t gidx = ((size_t)n * HW + i0 + i) * CMID + c;
        zt[i * 104 + c] = f2bf((zp0[gidx] + zp1[gidx]) * ll[i]);
    }
    __syncthreads();

    const int w = t >> 6, lane = t & 63, l15 = lane & 15, lg = lane >> 4;
    const int p0 = w * 16;

    bf16x8 af[3];
    #pragma unroll
    for (int f = 0; f < 3; ++f)
        af[f] = *(const bf16x8*)(zt + (p0 + l15) * 104 + f * 32 + lg * 8);

    #pragma unroll
    for (int ct = 0; ct < 12; ++ct) {
        f32x4 acc = (f32x4){0.f, 0.f, 0.f, 0.f};
        const unsigned short* wrow = wzb + (ct * 16 + l15) * CMID + lg * 8;
        #pragma unroll
        for (int f = 0; f < 3; ++f) {
            bf16x8 wf = *(const bf16x8*)(wrow + f * 32);
            acc = __builtin_amdgcn_mfma_f32_16x16x32_bf16(af[f], wf, acc, 0, 0, 0);
        }
        const int co = ct * 16 + l15;
        const int ibase = i0 + p0 + lg * 4;
        size_t xa = ((size_t)n * CIN + co) * HW + ibase;
        f32x4 xv = *(const f32x4*)(x + xa);
        f32x4 pv = *(const f32x4*)(pe + co * 14400 + blockIdx.x * 120 + p0 + lg * 4);
        const float bias = bz[co];
        f32x4 o;
        #pragma unroll
        for (int r = 0; r < 4; ++r) o[r] = xv[r] + pv[r] + acc[r] + bias;
        *(f32x4*)(out + xa) = o;
    }
}

// ---------------------------------------------------------------------------
extern "C" void kernel_launch(void* const* d_in, const int* in_sizes, int n_in,
                              void* d_out, int out_size, void* d_ws, size_t ws_size,
                              hipStream_t stream) {
    const float* x  = (const float*)d_in[0];
    const float* pe = (const float*)d_in[1];
    const float* wq = (const float*)d_in[2];
    const float* bq = (const float*)d_in[3];
    const float* wk = (const float*)d_in[4];
    const float* bk = (const float*)d_in[5];
    const float* wv = (const float*)d_in[6];
    const float* bv = (const float*)d_in[7];
    const float* wz = (const float*)d_in[8];
    const float* bz = (const float*)d_in[9];
    float* out = (float*)d_out;

    char* ws = (char*)d_ws;
    unsigned short* wqkvb = (unsigned short*)(ws);
    unsigned short* wzb   = (unsigned short*)(ws + 131072);
    unsigned short* Qb    = (unsigned short*)(ws + 196608);
    unsigned short* Kb    = (unsigned short*)(ws + 6488064);
    unsigned short* Vb    = (unsigned short*)(ws + 12779520);
    float*          zpb   = (float*)(ws + 19070976);
    float*          lpb   = (float*)(ws + 44236800);

    convw_kernel<<<288, 256, 0, stream>>>(wq, wk, wv, wz, wqkvb, wzb);
    qkv_kernel<<<dim3(64, 8), 256, 0, stream>>>(x, pe, wqkvb, bq, bk, bv,
                                                Qb, Kb, Vb);
    attn_kernel<<<512, 256, 0, stream>>>(Qb, Kb, Vb, zpb, lpb);
    zproj_kernel<<<dim3(64, 8), 256, 0, stream>>>(zpb, lpb, wzb, bz, x, pe, out);
}

// Round 3
// 129.947 us; speedup vs baseline: 5.2790x; 1.2350x over previous
//
#include <hip/hip_runtime.h>
#include <hip/hip_bf16.h>

#define HW 4096
#define CIN 192
#define CMID 96

typedef __attribute__((ext_vector_type(8))) short bf16x8;
typedef __attribute__((ext_vector_type(4))) float f32x4;
typedef __attribute__((ext_vector_type(16))) float f32x16;
typedef __attribute__((ext_vector_type(4))) unsigned int u32x4;

static __device__ __forceinline__ unsigned short f2bf(float f) {
    union { float f; unsigned int u; } v;
    v.f = f;
    unsigned int r = v.u + 0x7fffu + ((v.u >> 16) & 1u);
    return (unsigned short)(r >> 16);
}
static __device__ __forceinline__ float b2f(unsigned short h) {
    union { unsigned int u; float f; } v;
    v.u = ((unsigned int)h) << 16;
    return v.f;
}

static __device__ __forceinline__ void gload16(const void* g, void* l) {
    __builtin_amdgcn_global_load_lds(
        (const __attribute__((address_space(1))) unsigned int*)g,
        (__attribute__((address_space(3))) unsigned int*)l, 16, 0, 0);
}

// (1/64) * log2(e), folded into Q at projection time
#define SCQ (0.015625f * 1.44269504089f)

// ---------------------------------------------------------------------------
// Kernel 0: convert weights to bf16.  wqkvb: [3*96][192], wzb: [192][96]
// ---------------------------------------------------------------------------
__global__ __launch_bounds__(256) void convw_kernel(
    const float* __restrict__ wq, const float* __restrict__ wk,
    const float* __restrict__ wv, const float* __restrict__ wz,
    unsigned short* __restrict__ wqkvb, unsigned short* __restrict__ wzb)
{
    int idx = blockIdx.x * 256 + threadIdx.x;
    if (idx < 3 * CMID * CIN) {
        int m = idx / (CMID * CIN), r = idx % (CMID * CIN);
        const float* w = (m == 0) ? wq : ((m == 1) ? wk : wv);
        wqkvb[idx] = f2bf(w[r]);
    } else if (idx < 3 * CMID * CIN + CIN * CMID) {
        int r = idx - 3 * CMID * CIN;
        wzb[r] = f2bf(wz[r]);
    }
}

// ---------------------------------------------------------------------------
// Kernel 1: Q/K/V projections (bf16 MFMA).  Q pre-scaled by SCQ.
// Q,K out [n][i][96] (ushort4 packed stores); V out [n][96][i].
// ---------------------------------------------------------------------------
__global__ __launch_bounds__(256) void qkv_kernel(
    const float* __restrict__ x, const float* __restrict__ pe,
    const unsigned short* __restrict__ wqkvb,
    const float* __restrict__ bq, const float* __restrict__ bk,
    const float* __restrict__ bv,
    unsigned short* __restrict__ Q, unsigned short* __restrict__ K,
    unsigned short* __restrict__ V)
{
    const int n = blockIdx.y, i0 = blockIdx.x * 64, t = threadIdx.x;
    __shared__ unsigned short xt[64 * 200];

    for (int idx = t; idx < CIN * 64; idx += 256) {
        int c = idx >> 6, il = idx & 63;
        float v = x[((size_t)n * CIN + c) * HW + i0 + il]
                + pe[c * 14400 + blockIdx.x * 120 + il];
        xt[il * 200 + c] = f2bf(v);
    }
    __syncthreads();

    const int w = t >> 6, lane = t & 63, l15 = lane & 15, lg = lane >> 4;
    const int p0 = w * 16;

    // x fragment (identical lane layout as A-row frag and B-col frag)
    bf16x8 af[6];
    #pragma unroll
    for (int f = 0; f < 6; ++f)
        af[f] = *(const bf16x8*)(xt + (p0 + l15) * 200 + f * 32 + lg * 8);

    #pragma unroll
    for (int ct = 0; ct < 18; ++ct) {
        const int m = ct / 6, c6 = ct % 6;
        f32x4 acc = (f32x4){0.f, 0.f, 0.f, 0.f};
        const unsigned short* wrow = wqkvb + (ct * 16 + l15) * CIN + lg * 8;
        #pragma unroll
        for (int f = 0; f < 6; ++f) {
            bf16x8 wf = *(const bf16x8*)(wrow + f * 32);
            if (m < 2)  // D[co][pixel]: A = W rows(co), B = x cols(pixel)
                acc = __builtin_amdgcn_mfma_f32_16x16x32_bf16(wf, af[f], acc, 0, 0, 0);
            else        // D[pixel][co]: A = x rows(pixel), B = W cols(co)
                acc = __builtin_amdgcn_mfma_f32_16x16x32_bf16(af[f], wf, acc, 0, 0, 0);
        }
        if (m < 2) {
            // lane holds co = c6*16 + lg*4 + r for pixel = p0 + l15
            f32x4 bv4 = *(const f32x4*)(((m == 0) ? bq : bk) + c6 * 16 + lg * 4);
            ushort4 pk4;
            if (m == 0) {
                pk4.x = f2bf((acc[0] + bv4[0]) * SCQ);
                pk4.y = f2bf((acc[1] + bv4[1]) * SCQ);
                pk4.z = f2bf((acc[2] + bv4[2]) * SCQ);
                pk4.w = f2bf((acc[3] + bv4[3]) * SCQ);
            } else {
                pk4.x = f2bf(acc[0] + bv4[0]);
                pk4.y = f2bf(acc[1] + bv4[1]);
                pk4.z = f2bf(acc[2] + bv4[2]);
                pk4.w = f2bf(acc[3] + bv4[3]);
            }
            unsigned short* dst = ((m == 0) ? Q : K) + (size_t)n * HW * CMID;
            *(ushort4*)(dst + (size_t)(i0 + p0 + l15) * CMID + c6 * 16 + lg * 4) = pk4;
        } else {
            // lane holds pixel = p0 + lg*4 + r for co = c6*16 + l15
            const float bias = bv[c6 * 16 + l15];
            ushort4 pk4;
            pk4.x = f2bf(acc[0] + bias); pk4.y = f2bf(acc[1] + bias);
            pk4.z = f2bf(acc[2] + bias); pk4.w = f2bf(acc[3] + bias);
            *(ushort4*)(V + (size_t)n * CMID * HW + (size_t)(c6 * 16 + l15) * HW
                          + i0 + p0 + lg * 4) = pk4;
        }
    }
}

// ---------------------------------------------------------------------------
// Kernel 2: attention core, 32x32 MFMA, in-register softmax (no-max, Q
// pre-scaled).  S^T = mfma(K, Q); P stays in registers (cvt_pk + shfl_xor
// half-exchange); row sums via mfma(P, ones).  j-split over 2 block sets.
// ---------------------------------------------------------------------------
__global__ __launch_bounds__(256, 2) void attn_kernel(
    const unsigned short* __restrict__ Q, const unsigned short* __restrict__ K,
    const unsigned short* __restrict__ V,
    unsigned short* __restrict__ zp, float* __restrict__ lp)
{
    const int bid = blockIdx.x;
    const int xcd = bid & 7, kk_ = bid >> 3;
    const int g = xcd + 8 * (kk_ >> 5);
    const int bx = kk_ & 31;
    const int n = g >> 1, jh = g & 1;

    const int t = threadIdx.x, w = t >> 6, lane = t & 63;
    const int l31 = lane & 31, hi = lane >> 5;
    const int r7 = l31 & 7;
    const int ib = bx * 128 + w * 32;

    __shared__ unsigned short Ks[2][64 * 128];
    __shared__ unsigned short Vs[2][96 * 64];

    const unsigned short* Qb = Q + (size_t)n * HW * CMID;
    const unsigned short* Kb = K + (size_t)n * HW * CMID;
    const unsigned short* Vb = V + (size_t)n * CMID * HW;

    // Q as B-frag: col = i = l31, k = kc*16 + hi*8 + e
    bf16x8 qf[6];
    #pragma unroll
    for (int kc = 0; kc < 6; ++kc)
        qf[kc] = *(const bf16x8*)(Qb + (size_t)(ib + l31) * CMID + kc * 16 + hi * 8);

    // DMA source offsets, pre-swizzled: LDS[row][g] = src[row][g ^ (row&7)]
    int ksoff[4], vsoff[3];
    #pragma unroll
    for (int s = 0; s < 4; ++s) {
        int row = 4 * (w * 4 + s) + (lane >> 4);
        ksoff[s] = row * CMID + (((lane & 15) ^ (row & 7)) * 8);
    }
    #pragma unroll
    for (int s = 0; s < 3; ++s) {
        int c = 8 * (w * 3 + s) + (lane >> 3);
        vsoff[s] = c * HW + (((lane & 7) ^ (c & 7)) * 8);
    }

#define STAGE(J0, BUF) do {                                                        \
    _Pragma("unroll") for (int s = 0; s < 4; ++s)                                  \
        gload16(Kb + (size_t)(J0) * CMID + ksoff[s], &Ks[BUF][(w * 4 + s) * 512]); \
    _Pragma("unroll") for (int s = 0; s < 3; ++s)                                  \
        gload16(Vb + (size_t)(J0) + vsoff[s], &Vs[BUF][(w * 3 + s) * 512]);        \
} while (0)

    const int j00 = jh * 2048;
    STAGE(j00, 0);

    f32x16 O[3], Lon;
    #pragma unroll
    for (int e = 0; e < 16; ++e) { O[0][e] = 0.f; O[1][e] = 0.f; O[2][e] = 0.f; Lon[e] = 0.f; }

    bf16x8 onef;
    #pragma unroll
    for (int e = 0; e < 8; ++e) onef[e] = (short)0x3F80;  // bf16 1.0

    __syncthreads();

    for (int tt = 0; tt < 32; ++tt) {
        if (tt < 31) STAGE(j00 + (tt + 1) * 64, (tt + 1) & 1);

        const unsigned short* Kc = Ks[tt & 1];
        const unsigned short* Vc = Vs[tt & 1];

        // ---- S^T = mfma(A=K rows j, B=Q cols i): D[j][i], j=(reg&3)+8*(reg>>2)+4*hi
        f32x16 sacc[2];
        __builtin_amdgcn_s_setprio(1);
        #pragma unroll
        for (int s = 0; s < 2; ++s) {
            f32x16 a;
            #pragma unroll
            for (int e = 0; e < 16; ++e) a[e] = 0.f;
            const int row = s * 32 + l31;
            #pragma unroll
            for (int kc = 0; kc < 6; ++kc) {
                bf16x8 kf = *(const bf16x8*)(Kc + row * 128 + ((((kc * 2 + hi) ^ r7)) << 3));
                a = __builtin_amdgcn_mfma_f32_32x32x16_bf16(kf, qf[kc], a, 0, 0, 0);
            }
            sacc[s] = a;
        }
        __builtin_amdgcn_s_setprio(0);

        // ---- P = exp2(S) in-register; pack pairs to bf16
        unsigned pkk[2][4][2];
        #pragma unroll
        for (int s = 0; s < 2; ++s)
            #pragma unroll
            for (int q = 0; q < 4; ++q)
                #pragma unroll
                for (int rp = 0; rp < 2; ++rp) {
                    float lo = exp2f(sacc[s][q * 4 + 2 * rp]);
                    float hh = exp2f(sacc[s][q * 4 + 2 * rp + 1]);
                    unsigned d;
                    asm("v_cvt_pk_bf16_f32 %0, %1, %2" : "=v"(d) : "v"(lo), "v"(hh));
                    pkk[s][q][rp] = d;
                }

        // ---- redistribute to PV A-frags (exchange across lane+-32 halves)
        // target lane (hi,l31), chunk jc, word we needs pk[s=jc>>1][q=(jc&1)*2+hi][rp=we&1]
        // from holder half (we>>1).
        u32x4 pfu[4];
        #pragma unroll
        for (int s = 0; s < 2; ++s)
            #pragma unroll
            for (int p = 0; p < 2; ++p)
                #pragma unroll
                for (int rp = 0; rp < 2; ++rp) {
                    unsigned A = pkk[s][2 * p][rp], B = pkk[s][2 * p + 1][rp];
                    unsigned Ax = (unsigned)__shfl_xor((int)A, 32, 64);
                    unsigned Bx = (unsigned)__shfl_xor((int)B, 32, 64);
                    pfu[s * 2 + p][rp]     = hi ? Bx : A;   // holder half 0
                    pfu[s * 2 + p][2 + rp] = hi ? B  : Ax;  // holder half 1
                }

        // ---- O += P V ;  Lon += P * 1  (row sums)
        __builtin_amdgcn_s_setprio(1);
        #pragma unroll
        for (int jc = 0; jc < 4; ++jc) {
            bf16x8 pfv = __builtin_bit_cast(bf16x8, pfu[jc]);
            #pragma unroll
            for (int cc = 0; cc < 3; ++cc) {
                const int row = cc * 32 + l31;
                bf16x8 vf = *(const bf16x8*)(Vc + row * 64 + ((((jc * 2 + hi) ^ r7)) << 3));
                O[cc] = __builtin_amdgcn_mfma_f32_32x32x16_bf16(pfv, vf, O[cc], 0, 0, 0);
            }
            Lon = __builtin_amdgcn_mfma_f32_32x32x16_bf16(pfv, onef, Lon, 0, 0, 0);
        }
        __builtin_amdgcn_s_setprio(0);

        __syncthreads();
    }
#undef STAGE

    // ---- epilogue: unnormalized O (bf16) + row sums
    unsigned short* zb = zp + ((size_t)jh * 8 + n) * HW * CMID;
    #pragma unroll
    for (int cc = 0; cc < 3; ++cc)
        #pragma unroll
        for (int r = 0; r < 16; ++r) {
            int i = (r & 3) + 8 * (r >> 2) + 4 * hi;
            zb[(size_t)(ib + i) * CMID + cc * 32 + l31] = f2bf(O[cc][r]);
        }
    if (l31 == 0) {
        float* lb = lp + ((size_t)jh * 8 + n) * HW;
        #pragma unroll
        for (int r = 0; r < 16; ++r) {
            int i = (r & 3) + 8 * (r >> 2) + 4 * hi;
            lb[ib + i] = Lon[r];
        }
    }
}

// ---------------------------------------------------------------------------
// Kernel 3: combine j-halves, normalize, project back (MFMA), add residual.
// ---------------------------------------------------------------------------
__global__ __launch_bounds__(256) void zproj_kernel(
    const unsigned short* __restrict__ zp, const float* __restrict__ lp,
    const unsigned short* __restrict__ wzb, const float* __restrict__ bz,
    const float* __restrict__ x, const float* __restrict__ pe,
    float* __restrict__ out)
{
    const int n = blockIdx.y, i0 = blockIdx.x * 64, t = threadIdx.x;
    __shared__ unsigned short zt[64 * 104];
    __shared__ float ll[64];

    const unsigned short* zp0 = zp;
    const unsigned short* zp1 = zp + (size_t)8 * HW * CMID;
    const float* lp0 = lp;
    const float* lp1 = lp + (size_t)8 * HW;

    if (t < 64)
        ll[t] = 1.f / (lp0[(size_t)n * HW + i0 + t] + lp1[(size_t)n * HW + i0 + t]);
    __syncthreads();

    for (int idx = t; idx < 64 * 24; idx += 256) {
        int i = idx / 24, c4 = (idx % 24) * 4;
        size_t gidx = ((size_t)n * HW + i0 + i) * CMID + c4;
        ushort4 a = *(const ushort4*)(zp0 + gidx);
        ushort4 b = *(const ushort4*)(zp1 + gidx);
        float li = ll[i];
        zt[i * 104 + c4 + 0] = f2bf((b2f(a.x) + b2f(b.x)) * li);
        zt[i * 104 + c4 + 1] = f2bf((b2f(a.y) + b2f(b.y)) * li);
        zt[i * 104 + c4 + 2] = f2bf((b2f(a.z) + b2f(b.z)) * li);
        zt[i * 104 + c4 + 3] = f2bf((b2f(a.w) + b2f(b.w)) * li);
    }
    __syncthreads();

    const int w = t >> 6, lane = t & 63, l15 = lane & 15, lg = lane >> 4;
    const int p0 = w * 16;

    bf16x8 af[3];
    #pragma unroll
    for (int f = 0; f < 3; ++f)
        af[f] = *(const bf16x8*)(zt + (p0 + l15) * 104 + f * 32 + lg * 8);

    #pragma unroll
    for (int ct = 0; ct < 12; ++ct) {
        f32x4 acc = (f32x4){0.f, 0.f, 0.f, 0.f};
        const unsigned short* wrow = wzb + (ct * 16 + l15) * CMID + lg * 8;
        #pragma unroll
        for (int f = 0; f < 3; ++f) {
            bf16x8 wf = *(const bf16x8*)(wrow + f * 32);
            acc = __builtin_amdgcn_mfma_f32_16x16x32_bf16(af[f], wf, acc, 0, 0, 0);
        }
        const int co = ct * 16 + l15;
        const int ibase = i0 + p0 + lg * 4;
        size_t xa = ((size_t)n * CIN + co) * HW + ibase;
        f32x4 xv = *(const f32x4*)(x + xa);
        f32x4 pv = *(const f32x4*)(pe + co * 14400 + blockIdx.x * 120 + p0 + lg * 4);
        const float bias = bz[co];
        f32x4 o;
        #pragma unroll
        for (int r = 0; r < 4; ++r) o[r] = xv[r] + pv[r] + acc[r] + bias;
        *(f32x4*)(out + xa) = o;
    }
}

// ---------------------------------------------------------------------------
extern "C" void kernel_launch(void* const* d_in, const int* in_sizes, int n_in,
                              void* d_out, int out_size, void* d_ws, size_t ws_size,
                              hipStream_t stream) {
    const float* x  = (const float*)d_in[0];
    const float* pe = (const float*)d_in[1];
    const float* wq = (const float*)d_in[2];
    const float* bq = (const float*)d_in[3];
    const float* wk = (const float*)d_in[4];
    const float* bk = (const float*)d_in[5];
    const float* wv = (const float*)d_in[6];
    const float* bv = (const float*)d_in[7];
    const float* wz = (const float*)d_in[8];
    const float* bz = (const float*)d_in[9];
    float* out = (float*)d_out;

    char* ws = (char*)d_ws;
    // ws layout (bytes):
    //        0: wqkvb bf16 [288][192]      110,592 (pad 131072)
    //   131072: wzb   bf16 [192][96]        36,864 (pad 65536)
    //   196608: Q bf16 [8][4096][96]      6,291,456
    //  6488064: K bf16                    6,291,456
    // 12779520: V^T bf16 [8][96][4096]    6,291,456
    // 19070976: zp bf16 [2][8][4096][96] 12,582,912
    // 31653888: lp f32 [2][8][4096]         262,144   (end 31,916,032)
    unsigned short* wqkvb = (unsigned short*)(ws);
    unsigned short* wzb   = (unsigned short*)(ws + 131072);
    unsigned short* Qb    = (unsigned short*)(ws + 196608);
    unsigned short* Kb    = (unsigned short*)(ws + 6488064);
    unsigned short* Vb    = (unsigned short*)(ws + 12779520);
    unsigned short* zpb   = (unsigned short*)(ws + 19070976);
    float*          lpb   = (float*)(ws + 31653888);

    convw_kernel<<<288, 256, 0, stream>>>(wq, wk, wv, wz, wqkvb, wzb);
    qkv_kernel<<<dim3(64, 8), 256, 0, stream>>>(x, pe, wqkvb, bq, bk, bv,
                                                Qb, Kb, Vb);
    attn_kernel<<<512, 256, 0, stream>>>(Qb, Kb, Vb, zpb, lpb);
    zproj_kernel<<<dim3(64, 8), 256, 0, stream>>>(zpb, lpb, wzb, bz, x, pe, out);
}